// Round 1
// baseline (280.382 us; speedup 1.0000x reference)
//
#include <hip/hip_runtime.h>
#include <math.h>

// VectorQuantizer forward on MI355X.
//
// Key numerics facts (see analysis):
//  * probs == one_hot(argmax) to <=1ulp  -> z_q[n] = emb[idx[n]]
//  * argmax_j softmax((-d+g)/TAU) == argmax_j ( g[n,j] - ||e_j||^2 + 2 z_n.e_j )
//    (row-constant ||z_n||^2 and the positive 1/TAU scale drop out)
//  * LAMB*ortho ~ 1.5e-9 << ulp(loss~1.07) -> adding it in fp32 is a no-op; skipped.
//  * loss = mse * (1 + BETA^2), mse = mean((z_q - z)^2)
//  * perplexity from histogram of idx.

#define NROWS 16384
#define NE    1024
#define ED    256
#define EPSF  1e-10f

// ---------------- init: zero ws accumulators (ws is poisoned 0xAA every call)
__global__ void vq_init(int* __restrict__ cnt, double* __restrict__ mse_acc) {
    int t = blockIdx.x * blockDim.x + threadIdx.x;
    if (t < NE) cnt[t] = 0;
    if (t == 0) *mse_acc = 0.0;
}

// ---------------- e_norm[j] = ||emb_j||^2 ; one wave per code
__global__ void vq_enorm(const float* __restrict__ emb, float* __restrict__ enorm) {
    int gid  = blockIdx.x * blockDim.x + threadIdx.x;
    int code = gid >> 6;
    int l    = gid & 63;
    const float* e = emb + (size_t)code * ED;
    float s = 0.f;
#pragma unroll
    for (int q = 0; q < 4; ++q) { float v = e[l + (q << 6)]; s += v * v; }
#pragma unroll
    for (int o = 32; o; o >>= 1) s += __shfl_down(s, o);
    if (l == 0) enorm[code] = s;
}

// pack (value, code) into an orderable u64 for atomicMax; ties -> smaller code
// (matches np.argmax first-max semantics).
__device__ inline unsigned long long packMax(float v, int code) {
    unsigned int b   = __float_as_uint(v);
    unsigned int key = (b & 0x80000000u) ? ~b : (b | 0x80000000u);
    return ((unsigned long long)key << 32) | (unsigned int)(NE - 1 - code);
}

// ---------------- main fused kernel
// Tile: BM=64 rows x BN=128 codes, K=256 staged in LDS chunks of KC=32.
// 512 threads; micro-tile 4x4 per thread (tm = t>>5 rows, tn = t&31 cols so
// u-loads / Bs-reads are lane-contiguous).
#define BM 64
#define BN 128
#define KC 32

__global__ __launch_bounds__(512) void vq_main(
        const float* __restrict__ z, const float* __restrict__ emb,
        const float* __restrict__ u, const float* __restrict__ enorm,
        int* __restrict__ cnt, double* __restrict__ mse_acc,
        float* __restrict__ out)
{
    __shared__ float As[KC][BM];          // [k][m]  (z tile, transposed)
    __shared__ float Bs[KC][BN];          // [k][n]  (emb tile, transposed)
    __shared__ unsigned long long best[BM];
    __shared__ int   rowIdx[BM];
    __shared__ float redbuf[8];

    const int t  = threadIdx.x;
    const int tm = t >> 5;                // 0..15  (row group)
    const int tn = t & 31;                // 0..31  (col group)
    const int m0 = blockIdx.x * BM;

    for (int r = t; r < BM; r += 512) best[r] = 0ull;   // below any real key

    for (int nc = 0; nc < NE / BN; ++nc) {
        float acc[4][4] = {{0.f}};

        for (int kc = 0; kc < ED; kc += KC) {
            __syncthreads();
            // stage A: 64 rows x 32 k = 512 float4, one per thread
            {
                int row = t >> 3;
                int k4  = (t & 7) << 2;
                const float4 v = *(const float4*)&z[(size_t)(m0 + row) * ED + kc + k4];
                As[k4 + 0][row] = v.x; As[k4 + 1][row] = v.y;
                As[k4 + 2][row] = v.z; As[k4 + 3][row] = v.w;
            }
            // stage B: 128 codes x 32 k = 1024 float4, two per thread
#pragma unroll
            for (int h = 0; h < 2; ++h) {
                int code = (t >> 3) + (h << 6);
                int k4   = (t & 7) << 2;
                const float4 v = *(const float4*)&emb[(size_t)(nc * BN + code) * ED + kc + k4];
                Bs[k4 + 0][code] = v.x; Bs[k4 + 1][code] = v.y;
                Bs[k4 + 2][code] = v.z; Bs[k4 + 3][code] = v.w;
            }
            __syncthreads();
#pragma unroll
            for (int k = 0; k < KC; ++k) {
                const float4 a = *(const float4*)&As[k][tm << 2];
                const float4 b = *(const float4*)&Bs[k][tn << 2];
                acc[0][0] = fmaf(a.x, b.x, acc[0][0]); acc[0][1] = fmaf(a.x, b.y, acc[0][1]);
                acc[0][2] = fmaf(a.x, b.z, acc[0][2]); acc[0][3] = fmaf(a.x, b.w, acc[0][3]);
                acc[1][0] = fmaf(a.y, b.x, acc[1][0]); acc[1][1] = fmaf(a.y, b.y, acc[1][1]);
                acc[1][2] = fmaf(a.y, b.z, acc[1][2]); acc[1][3] = fmaf(a.y, b.w, acc[1][3]);
                acc[2][0] = fmaf(a.z, b.x, acc[2][0]); acc[2][1] = fmaf(a.z, b.y, acc[2][1]);
                acc[2][2] = fmaf(a.z, b.z, acc[2][2]); acc[2][3] = fmaf(a.z, b.w, acc[2][3]);
                acc[3][0] = fmaf(a.w, b.x, acc[3][0]); acc[3][1] = fmaf(a.w, b.y, acc[3][1]);
                acc[3][2] = fmaf(a.w, b.z, acc[3][2]); acc[3][3] = fmaf(a.w, b.w, acc[3][3]);
            }
        }

        // epilogue for this code chunk: gumbel noise + per-row running argmax
        const int c0 = nc * BN + (tn << 2);
        const float4 en = *(const float4*)&enorm[c0];
#pragma unroll
        for (int im = 0; im < 4; ++im) {
            const int row = (tm << 2) + im;
            const float4 uu = *(const float4*)&u[(size_t)(m0 + row) * NE + c0];
            const float s0 = 2.f * acc[im][0] - en.x - logf(-logf(uu.x + EPSF) + EPSF);
            const float s1 = 2.f * acc[im][1] - en.y - logf(-logf(uu.y + EPSF) + EPSF);
            const float s2 = 2.f * acc[im][2] - en.z - logf(-logf(uu.z + EPSF) + EPSF);
            const float s3 = 2.f * acc[im][3] - en.w - logf(-logf(uu.w + EPSF) + EPSF);
            float bv = s0; int bc = c0;
            if (s1 > bv) { bv = s1; bc = c0 + 1; }
            if (s2 > bv) { bv = s2; bc = c0 + 2; }
            if (s3 > bv) { bv = s3; bc = c0 + 3; }
            atomicMax(&best[row], packMax(bv, bc));
        }
    }
    __syncthreads();

    if (t < BM) {
        unsigned long long p = best[t];
        int code = NE - 1 - (int)(p & 0xFFFFFFFFu);
        rowIdx[t] = code;
        atomicAdd(&cnt[code], 1);   // histogram for perplexity
    }
    __syncthreads();

    // write z_q_st = z + (emb[idx] - z) and accumulate mse.
    // d_out layout: [0]=loss, [1..NROWS*ED]=z_q_st, [last]=perplexity -> the +1
    // offset breaks 16B alignment, so use coalesced scalar dword stores
    // (thread handles dims d, d+64, d+128, d+192).
    float lmse = 0.f;
#pragma unroll
    for (int rr = 0; rr < 8; ++rr) {
        const int row = (rr << 3) + (t >> 6);
        const int d   = t & 63;
        const int j   = rowIdx[row];
        const size_t zb = (size_t)(m0 + row) * ED;
        const size_t eb = (size_t)j * ED;
#pragma unroll
        for (int q = 0; q < 4; ++q) {
            const int dim = d + (q << 6);
            const float zq = emb[eb + dim];
            const float zz = z[zb + dim];
            const float df = zq - zz;
            out[1 + zb + dim] = zz + df;       // matches ref: z + sg(z_q - z)
            lmse = fmaf(df, df, lmse);
        }
    }
#pragma unroll
    for (int o = 32; o; o >>= 1) lmse += __shfl_down(lmse, o);
    if ((t & 63) == 0) redbuf[t >> 6] = lmse;
    __syncthreads();
    if (t == 0) {
        float s = 0.f;
#pragma unroll
        for (int i = 0; i < 8; ++i) s += redbuf[i];
        atomicAdd(mse_acc, (double)s);
    }
}

// ---------------- finalize: loss + perplexity
__global__ void vq_final(const int* __restrict__ cnt, const double* __restrict__ mse_acc,
                         float* __restrict__ out) {
    __shared__ double red[16];
    const int t = threadIdx.x;          // 1024 threads
    const float em   = (float)cnt[t] / (float)NROWS;
    const float term = em * logf(em + EPSF);
    double s = (double)term;
#pragma unroll
    for (int o = 32; o; o >>= 1) s += __shfl_down(s, o);
    if ((t & 63) == 0) red[t >> 6] = s;
    __syncthreads();
    if (t == 0) {
        double tot = 0.0;
#pragma unroll
        for (int i = 0; i < 16; ++i) tot += red[i];
        const float perp = expf((float)(-tot));
        const double mse = *mse_acc / (double)((size_t)NROWS * ED);
        // loss = emb_loss + BETA*commit = mse*(1 + 0.25^2); LAMB*ortho ~1.5e-9 is
        // sub-ULP of loss (~1.07) in fp32 -> omitted (exact no-op).
        out[0] = (float)(mse * 1.0625);
        out[1 + (size_t)NROWS * ED] = perp;
    }
}

extern "C" void kernel_launch(void* const* d_in, const int* in_sizes, int n_in,
                              void* d_out, int out_size, void* d_ws, size_t ws_size,
                              hipStream_t stream) {
    const float* z   = (const float*)d_in[0];
    const float* emb = (const float*)d_in[1];
    const float* u   = (const float*)d_in[2];
    float* out = (float*)d_out;

    double* mse_acc = (double*)d_ws;
    int*    cnt     = (int*)((char*)d_ws + 64);
    float*  enorm   = (float*)((char*)d_ws + 8192);

    vq_init<<<4, 256, 0, stream>>>(cnt, mse_acc);
    vq_enorm<<<256, 256, 0, stream>>>(emb, enorm);
    vq_main<<<NROWS / BM, 512, 0, stream>>>(z, emb, u, enorm, cnt, mse_acc, out);
    vq_final<<<1, 1024, 0, stream>>>(cnt, mse_acc, out);
}

// Round 2
// 227.049 us; speedup vs baseline: 1.2349x; 1.2349x over previous
//
#include <hip/hip_runtime.h>
#include <math.h>

// VectorQuantizer forward on MI355X — round 2.
//
// Numerics facts (verified round 1, absmax 4.9e-4 ≈ perplexity float rounding):
//  * probs == one_hot(argmax) to <=1ulp  -> z_q[n] = emb[idx[n]]
//  * argmax_j softmax((-d+g)/TAU) == argmax_j ( g[n,j] - ||e_j||^2 + 2 z_n.e_j )
//  * LAMB*ortho ~ 1.5e-9 is sub-ULP of loss (~1.07) -> exact no-op, skipped.
//  * loss = mse * (1 + BETA^2), mse = mean((z_q - z)^2)
//
// R2 changes (LDS-throughput + occupancy fixes):
//  * 8x8 micro-tile (64 FMA / 64 B LDS per thread-k; a-frags broadcast -> VALU-bound)
//  * grid 256x4 (BM=64 rows x BN=256 codes), 4 blocks/CU, cross-block argmax via
//    global u64 atomicMax on packed (value,code) keys
//  * LDS pads +4 floats: ds_read_b128 stays 16B-aligned, staging writes drop from
//    8-way to free 2-way bank conflicts

#define NROWS 16384
#define NE    1024
#define ED    256
#define EPSF  1e-10f

#define BM   64
#define BN   256
#define KC   16
#define APAD 4
#define BPAD 4

// ---------------- init: zero ws accumulators (ws is poisoned 0xAA every call)
__global__ void vq_init(int* __restrict__ cnt, double* __restrict__ mse_acc,
                        unsigned long long* __restrict__ best) {
    int t = blockIdx.x * blockDim.x + threadIdx.x;   // 16384 threads
    best[t] = 0ull;                                  // below any real packed key
    if (t < NE) cnt[t] = 0;
    if (t == 0) *mse_acc = 0.0;
}

// ---------------- e_norm[j] = ||emb_j||^2 ; one wave per code
__global__ void vq_enorm(const float* __restrict__ emb, float* __restrict__ enorm) {
    int gid  = blockIdx.x * blockDim.x + threadIdx.x;
    int code = gid >> 6;
    int l    = gid & 63;
    const float* e = emb + (size_t)code * ED;
    float s = 0.f;
#pragma unroll
    for (int q = 0; q < 4; ++q) { float v = e[l + (q << 6)]; s += v * v; }
#pragma unroll
    for (int o = 32; o; o >>= 1) s += __shfl_down(s, o);
    if (l == 0) enorm[code] = s;
}

// pack (value, code) into an orderable u64 for atomicMax; ties -> smaller code
// (matches np.argmax first-max semantics).
__device__ inline unsigned long long packMax(float v, int code) {
    unsigned int b   = __float_as_uint(v);
    unsigned int key = (b & 0x80000000u) ? ~b : (b | 0x80000000u);
    return ((unsigned long long)key << 32) | (unsigned int)(NE - 1 - code);
}

// ---------------- GEMM + gumbel + per-row argmax partials
// 256 threads: tm = t>>5 (0..7) owns rows {tm*4..+3, +32}; tn = t&31 owns cols
// {tn*4..+3, +128}. All LDS frag reads are 16B-aligned b128 with 16B lane stride
// (conflict-free); a-frags are 2-address half-wave broadcasts.
__global__ __launch_bounds__(256, 4) void vq_gemm(
        const float* __restrict__ z, const float* __restrict__ emb,
        const float* __restrict__ u, const float* __restrict__ enorm,
        unsigned long long* __restrict__ best)
{
    __shared__ float As[KC][BM + APAD];
    __shared__ float Bs[KC][BN + BPAD];
    __shared__ unsigned long long bl[BM];

    const int t  = threadIdx.x;
    const int tm = t >> 5;
    const int tn = t & 31;
    const int m0 = blockIdx.x * BM;
    const int n0 = blockIdx.y * BN;

    if (t < BM) bl[t] = 0ull;

    float acc[8][8] = {{0.f}};

    const int arow = t >> 2;           // staging: row/code index
    const int ak4  = (t & 3) << 2;     // staging: k offset (0,4,8,12)

    for (int kc = 0; kc < ED; kc += KC) {
        __syncthreads();
        // stage A: 64 rows x 16 k = 256 float4, one per thread
        {
            const float4 v = *(const float4*)&z[(size_t)(m0 + arow) * ED + kc + ak4];
            As[ak4 + 0][arow] = v.x; As[ak4 + 1][arow] = v.y;
            As[ak4 + 2][arow] = v.z; As[ak4 + 3][arow] = v.w;
        }
        // stage B: 256 codes x 16 k = 1024 float4, four per thread
#pragma unroll
        for (int h = 0; h < 4; ++h) {
            const int code = arow + (h << 6);
            const float4 v = *(const float4*)&emb[(size_t)(n0 + code) * ED + kc + ak4];
            Bs[ak4 + 0][code] = v.x; Bs[ak4 + 1][code] = v.y;
            Bs[ak4 + 2][code] = v.z; Bs[ak4 + 3][code] = v.w;
        }
        __syncthreads();
#pragma unroll
        for (int k = 0; k < KC; ++k) {
            const float4 a0 = *(const float4*)&As[k][tm << 2];
            const float4 a1 = *(const float4*)&As[k][(tm << 2) + 32];
            const float4 b0 = *(const float4*)&Bs[k][tn << 2];
            const float4 b1 = *(const float4*)&Bs[k][(tn << 2) + 128];
            const float av[8] = {a0.x, a0.y, a0.z, a0.w, a1.x, a1.y, a1.z, a1.w};
            const float bv[8] = {b0.x, b0.y, b0.z, b0.w, b1.x, b1.y, b1.z, b1.w};
#pragma unroll
            for (int i = 0; i < 8; ++i)
#pragma unroll
                for (int j = 0; j < 8; ++j)
                    acc[i][j] = fmaf(av[i], bv[j], acc[i][j]);
        }
    }

    // epilogue: gumbel noise + per-row argmax over this block's 256 codes
    const int c0 = n0 + (tn << 2);
    const float4 en0 = *(const float4*)&enorm[c0];
    const float4 en1 = *(const float4*)&enorm[c0 + 128];
    const float en[8] = {en0.x, en0.y, en0.z, en0.w, en1.x, en1.y, en1.z, en1.w};
#pragma unroll
    for (int ra = 0; ra < 2; ++ra)
#pragma unroll
    for (int i = 0; i < 4; ++i) {
        const int row = (ra << 5) + (tm << 2) + i;
        const int ia  = (ra << 2) + i;
        const float4 u0 = *(const float4*)&u[(size_t)(m0 + row) * NE + c0];
        const float4 u1 = *(const float4*)&u[(size_t)(m0 + row) * NE + c0 + 128];
        const float uv[8] = {u0.x, u0.y, u0.z, u0.w, u1.x, u1.y, u1.z, u1.w};
        float bvv = -1e30f; int bc = 0;
#pragma unroll
        for (int j = 0; j < 8; ++j) {
            const float g = -logf(-logf(uv[j] + EPSF) + EPSF);
            const float s = 2.f * acc[ia][j] - en[j] + g;
            const int   c = c0 + ((j >> 2) << 7) + (j & 3);
            // strict > with ascending j would pick later ties within a thread;
            // packMax handles cross-thread ties; within-thread cols ascend, so
            // keep first-max via >.
            if (s > bvv) { bvv = s; bc = c; }
        }
        atomicMax(&bl[row], packMax(bvv, bc));
    }
    __syncthreads();
    if (t < BM) atomicMax(&best[m0 + t], bl[t]);
}

// ---------------- gather z_q, write z_q_st, accumulate mse, histogram
__global__ __launch_bounds__(256) void vq_out(
        const float* __restrict__ z, const float* __restrict__ emb,
        const unsigned long long* __restrict__ best,
        int* __restrict__ cnt, double* __restrict__ mse_acc,
        float* __restrict__ out)
{
    __shared__ int   ridx[BM];
    __shared__ float redbuf[4];
    const int t  = threadIdx.x;
    const int m0 = blockIdx.x * BM;

    if (t < BM) {
        const unsigned long long p = best[m0 + t];
        const int code = NE - 1 - (int)(p & 0xFFFFFFFFu);
        ridx[t] = code;
        atomicAdd(&cnt[code], 1);
    }
    __syncthreads();

    // d_out layout: [0]=loss, [1..N*ED]=z_q_st, [last]=perplexity. The +1 offset
    // breaks 16B alignment -> coalesced scalar dword stores.
    float lmse = 0.f;
#pragma unroll
    for (int rr = 0; rr < 16; ++rr) {
        const int row = (rr << 2) + (t >> 6);
        const int d   = t & 63;
        const int j   = ridx[row];
        const size_t zb = (size_t)(m0 + row) * ED;
        const size_t eb = (size_t)j * ED;
#pragma unroll
        for (int q = 0; q < 4; ++q) {
            const int dim = d + (q << 6);
            const float df = emb[eb + dim] - z[zb + dim];
            out[1 + zb + dim] = z[zb + dim] + df;
            lmse = fmaf(df, df, lmse);
        }
    }
#pragma unroll
    for (int o = 32; o; o >>= 1) lmse += __shfl_down(lmse, o);
    if ((t & 63) == 0) redbuf[t >> 6] = lmse;
    __syncthreads();
    if (t == 0) {
        float s = redbuf[0] + redbuf[1] + redbuf[2] + redbuf[3];
        atomicAdd(mse_acc, (double)s);
    }
}

// ---------------- finalize: loss + perplexity
__global__ void vq_final(const int* __restrict__ cnt, const double* __restrict__ mse_acc,
                         float* __restrict__ out) {
    __shared__ double red[16];
    const int t = threadIdx.x;          // 1024 threads
    const float em   = (float)cnt[t] / (float)NROWS;
    const float term = em * logf(em + EPSF);
    double s = (double)term;
#pragma unroll
    for (int o = 32; o; o >>= 1) s += __shfl_down(s, o);
    if ((t & 63) == 0) red[t >> 6] = s;
    __syncthreads();
    if (t == 0) {
        double tot = 0.0;
#pragma unroll
        for (int i = 0; i < 16; ++i) tot += red[i];
        const float perp = expf((float)(-tot));
        const double mse = *mse_acc / (double)((size_t)NROWS * ED);
        out[0] = (float)(mse * 1.0625);          // mse*(1+BETA^2); ortho sub-ULP
        out[1 + (size_t)NROWS * ED] = perp;
    }
}

extern "C" void kernel_launch(void* const* d_in, const int* in_sizes, int n_in,
                              void* d_out, int out_size, void* d_ws, size_t ws_size,
                              hipStream_t stream) {
    const float* z   = (const float*)d_in[0];
    const float* emb = (const float*)d_in[1];
    const float* u   = (const float*)d_in[2];
    float* out = (float*)d_out;

    double*             mse_acc = (double*)d_ws;
    int*                cnt     = (int*)((char*)d_ws + 64);
    float*              enorm   = (float*)((char*)d_ws + 64 + 4096);
    unsigned long long* best    = (unsigned long long*)((char*)d_ws + 64 + 4096 + 4096);

    vq_init<<<NROWS / 256, 256, 0, stream>>>(cnt, mse_acc, best);
    vq_enorm<<<256, 256, 0, stream>>>(emb, enorm);
    vq_gemm<<<dim3(NROWS / BM, NE / BN), 256, 0, stream>>>(z, emb, u, enorm, best);
    vq_out<<<NROWS / BM, 256, 0, stream>>>(z, emb, best, cnt, mse_acc, out);
    vq_final<<<1, 1024, 0, stream>>>(cnt, mse_acc, out);
}

// Round 3
// 198.216 us; speedup vs baseline: 1.4145x; 1.1455x over previous
//
#include <hip/hip_runtime.h>
#include <math.h>
#include <stdint.h>

// VectorQuantizer forward on MI355X — round 3: fp16-split MFMA GEMM.
//
// Numerics (verified R1/R2, absmax 4.9e-4 = perplexity float rounding):
//  * probs == one_hot(argmax)           -> z_q[n] = emb[idx[n]]
//  * argmax_j softmax((-d+g)/TAU) == argmax_j ( g[n,j] - ||e_j||^2 + 2 z_n.e_j )
//  * LAMB*ortho ~1.5e-9 sub-ULP of loss -> skipped (exact no-op in fp32)
//  * loss = mse*(1+BETA^2)
// R3: dot via fp16 split x = hi + lo*2^-11 (lo stored pre-scaled by 2048 so it
// stays in fp16-normal range regardless of MFMA denorm behavior):
//   z.e = zh.eh + (zh.el' + zl'.eh)*2^-11   (lo.lo ~2^-22 rel, dropped)
// -> error ~2e-6, same order as the fp32-FMA kernel that passed.

#define NROWS 16384
#define NE    1024
#define ED    256
#define EPSF  1e-10f
#define INV2048 4.8828125e-4f

typedef _Float16 half_t;
typedef __attribute__((ext_vector_type(4))) _Float16 half4;
typedef __attribute__((ext_vector_type(8))) _Float16 half8;
typedef __attribute__((ext_vector_type(16))) float floatx16;

__device__ __forceinline__ void gl_lds16(const half_t* g, half_t* l) {
    __builtin_amdgcn_global_load_lds(
        (const __attribute__((address_space(1))) uint32_t*)g,
        (__attribute__((address_space(3))) uint32_t*)l, 16, 0, 0);
}

// pack (value, code) into an orderable u64 for atomicMax; ties -> smaller code
__device__ __forceinline__ unsigned long long packMax(float v, int code) {
    unsigned int b   = __float_as_uint(v);
    unsigned int key = (b & 0x80000000u) ? ~b : (b | 0x80000000u);
    return ((unsigned long long)key << 32) | (unsigned int)(NE - 1 - code);
}

// ---------------- split z/emb into fp16 hi + 2048*lo; zero ws accumulators
__global__ __launch_bounds__(256) void vq_split(
        const float* __restrict__ z, const float* __restrict__ emb,
        half_t* __restrict__ zh, half_t* __restrict__ zl,
        half_t* __restrict__ eh, half_t* __restrict__ el,
        unsigned long long* __restrict__ best, int* __restrict__ cnt,
        double* __restrict__ mse_acc)
{
    const int gid = blockIdx.x * 256 + threadIdx.x;      // 0 .. 1114111
    const int ZQ4 = NROWS * ED / 4;                      // 1048576
    const bool is_z = gid < ZQ4;
    const float4 v = is_z ? ((const float4*)z)[gid]
                          : ((const float4*)emb)[gid - ZQ4];
    const float x[4] = {v.x, v.y, v.z, v.w};
    half4 h, l;
#pragma unroll
    for (int i = 0; i < 4; ++i) {
        const half_t hi = (half_t)x[i];
        const float  lo = (x[i] - (float)hi) * 2048.0f;  // exact diff, exact scale
        h[i] = hi; l[i] = (half_t)lo;
    }
    if (is_z) {
        *(half4*)&zh[(size_t)gid * 4] = h;
        *(half4*)&zl[(size_t)gid * 4] = l;
    } else {
        *(half4*)&eh[(size_t)(gid - ZQ4) * 4] = h;
        *(half4*)&el[(size_t)(gid - ZQ4) * 4] = l;
    }
    if (gid < NROWS) best[gid] = 0ull;
    if (gid < NE)    cnt[gid]  = 0;
    if (gid == 0)    *mse_acc  = 0.0;
}

// ---------------- e_norm[j] = ||emb_j||^2 (fp32 source)
__global__ void vq_enorm(const float* __restrict__ emb, float* __restrict__ enorm) {
    int gid  = blockIdx.x * blockDim.x + threadIdx.x;
    int code = gid >> 6;
    int lane = gid & 63;
    const float* e = emb + (size_t)code * ED;
    float s = 0.f;
#pragma unroll
    for (int q = 0; q < 4; ++q) { float v = e[lane + (q << 6)]; s += v * v; }
#pragma unroll
    for (int o = 32; o; o >>= 1) s += __shfl_down(s, o);
    if (lane == 0) enorm[code] = s;
}

// ---------------- MFMA GEMM + gumbel + argmax partials
// 128x128 tile, 4 waves in 2x2, each wave 2x2 of 32x32x16 f16 MFMA, BK=64.
#define BK 64
__global__ __launch_bounds__(256, 2) void vq_gemm(
        const half_t* __restrict__ zh, const half_t* __restrict__ zl,
        const half_t* __restrict__ eh, const half_t* __restrict__ el,
        const float* __restrict__ u, const float* __restrict__ enorm,
        unsigned long long* __restrict__ best)
{
    __shared__ __align__(16) half_t Ah[128 * BK], Al[128 * BK],
                                    Bh[128 * BK], Bl[128 * BK];
    __shared__ unsigned long long blmax[128];

    const int t    = threadIdx.x;
    const int w    = t >> 6;
    const int lane = t & 63;
    const int m0 = blockIdx.x * 128, n0 = blockIdx.y * 128;
    const int wm = (w >> 1) * 64,    wn = (w & 1) * 64;
    const int lrow = lane & 31;
    const int lk   = (lane >> 5) << 3;

    if (t < 128) blmax[t] = 0ull;

    floatx16 accH[2][2] = {};
    floatx16 accX[2][2] = {};

    for (int kc = 0; kc < ED; kc += BK) {
        __syncthreads();
#pragma unroll
        for (int it = 0; it < 4; ++it) {
            const int c       = it * 256 + t;                 // 16B-chunk id 0..1023
            const int ldsbase = (it * 256 + w * 64) * 8;      // wave-uniform dest
            const int m       = c >> 3;
            const int k8      = (c & 7) << 3;
            const size_t ga = (size_t)(m0 + m) * ED + kc + k8;
            const size_t gb = (size_t)(n0 + m) * ED + kc + k8;
            gl_lds16(zh + ga, Ah + ldsbase);
            gl_lds16(zl + ga, Al + ldsbase);
            gl_lds16(eh + gb, Bh + ldsbase);
            gl_lds16(el + gb, Bl + ldsbase);
        }
        __syncthreads();   // drains vmcnt (global_load_lds) + makes LDS visible
#pragma unroll
        for (int ks = 0; ks < BK / 16; ++ks) {
            const int ko = ks * 16 + lk;
            half8 ah[2], al[2], bh[2], bl[2];
#pragma unroll
            for (int i = 0; i < 2; ++i) {
                const int ar = wm + i * 32 + lrow;
                const int br = wn + i * 32 + lrow;
                ah[i] = *(const half8*)&Ah[ar * BK + ko];
                al[i] = *(const half8*)&Al[ar * BK + ko];
                bh[i] = *(const half8*)&Bh[br * BK + ko];
                bl[i] = *(const half8*)&Bl[br * BK + ko];
            }
#pragma unroll
            for (int i = 0; i < 2; ++i)
#pragma unroll
            for (int j = 0; j < 2; ++j) {
                accH[i][j] = __builtin_amdgcn_mfma_f32_32x32x16_f16(ah[i], bh[j], accH[i][j], 0, 0, 0);
                accX[i][j] = __builtin_amdgcn_mfma_f32_32x32x16_f16(ah[i], bl[j], accX[i][j], 0, 0, 0);
                accX[i][j] = __builtin_amdgcn_mfma_f32_32x32x16_f16(al[i], bh[j], accX[i][j], 0, 0, 0);
            }
        }
    }

    // epilogue: gumbel + per-row argmax. C/D layout (m74/m101):
    // col = lane&31, row = (reg&3) + 8*(reg>>2) + 4*(lane>>5)
    const int   col0 = n0 + wn + lrow;
    const float en0  = enorm[col0];
    const float en1  = enorm[col0 + 32];
    const int   hw   = lane >> 5;
#pragma unroll
    for (int i = 0; i < 2; ++i) {
#pragma unroll
        for (int r = 0; r < 16; ++r) {
            const int lr = wm + i * 32 + (r & 3) + ((r >> 2) << 3) + (hw << 2);
            const size_t urow = (size_t)(m0 + lr) * NE;
            const float d0 = accH[i][0][r] + accX[i][0][r] * INV2048;
            const float d1 = accH[i][1][r] + accX[i][1][r] * INV2048;
            const float u0 = u[urow + col0];
            const float u1 = u[urow + col0 + 32];
            const float g0 = -__logf(-__logf(u0 + EPSF) + EPSF);
            const float g1 = -__logf(-__logf(u1 + EPSF) + EPSF);
            const float s0 = 2.f * d0 - en0 + g0;
            const float s1 = 2.f * d1 - en1 + g1;
            float sb; int cb;
            if (s1 > s0) { sb = s1; cb = col0 + 32; } else { sb = s0; cb = col0; }
            atomicMax(&blmax[lr], packMax(sb, cb));
        }
    }
    __syncthreads();
    if (t < 128) atomicMax(&best[m0 + t], blmax[t]);
}

// ---------------- gather z_q, write z_q_st, accumulate mse, histogram
__global__ __launch_bounds__(256) void vq_out(
        const float* __restrict__ z, const float* __restrict__ emb,
        const unsigned long long* __restrict__ best,
        int* __restrict__ cnt, double* __restrict__ mse_acc,
        float* __restrict__ out)
{
    __shared__ int   ridx[64];
    __shared__ float redbuf[4];
    const int t  = threadIdx.x;
    const int m0 = blockIdx.x * 64;

    if (t < 64) {
        const unsigned long long p = best[m0 + t];
        const int code = NE - 1 - (int)(p & 0xFFFFFFFFu);
        ridx[t] = code;
        atomicAdd(&cnt[code], 1);
    }
    __syncthreads();

    // d_out: [0]=loss, [1..N*ED]=z_q_st, [last]=perplexity (+1 breaks 16B
    // alignment -> coalesced scalar dword stores)
    float lmse = 0.f;
#pragma unroll
    for (int rr = 0; rr < 16; ++rr) {
        const int row = (rr << 2) + (t >> 6);
        const int d   = t & 63;
        const int j   = ridx[row];
        const size_t zb = (size_t)(m0 + row) * ED;
        const size_t eb = (size_t)j * ED;
#pragma unroll
        for (int q = 0; q < 4; ++q) {
            const int dim = d + (q << 6);
            const float df = emb[eb + dim] - z[zb + dim];
            out[1 + zb + dim] = z[zb + dim] + df;
            lmse = fmaf(df, df, lmse);
        }
    }
#pragma unroll
    for (int o = 32; o; o >>= 1) lmse += __shfl_down(lmse, o);
    if ((t & 63) == 0) redbuf[t >> 6] = lmse;
    __syncthreads();
    if (t == 0) {
        float s = redbuf[0] + redbuf[1] + redbuf[2] + redbuf[3];
        atomicAdd(mse_acc, (double)s);
    }
}

// ---------------- finalize: loss + perplexity
__global__ void vq_final(const int* __restrict__ cnt, const double* __restrict__ mse_acc,
                         float* __restrict__ out) {
    __shared__ double red[16];
    const int t = threadIdx.x;          // 1024 threads
    const float em   = (float)cnt[t] / (float)NROWS;
    const float term = em * logf(em + EPSF);
    double s = (double)term;
#pragma unroll
    for (int o = 32; o; o >>= 1) s += __shfl_down(s, o);
    if ((t & 63) == 0) red[t >> 6] = s;
    __syncthreads();
    if (t == 0) {
        double tot = 0.0;
#pragma unroll
        for (int i = 0; i < 16; ++i) tot += red[i];
        const float perp = expf((float)(-tot));
        const double mse = *mse_acc / (double)((size_t)NROWS * ED);
        out[0] = (float)(mse * 1.0625);          // mse*(1+BETA^2); ortho sub-ULP
        out[1 + (size_t)NROWS * ED] = perp;
    }
}

extern "C" void kernel_launch(void* const* d_in, const int* in_sizes, int n_in,
                              void* d_out, int out_size, void* d_ws, size_t ws_size,
                              hipStream_t stream) {
    const float* z   = (const float*)d_in[0];
    const float* emb = (const float*)d_in[1];
    const float* u   = (const float*)d_in[2];
    float* out = (float*)d_out;

    double*             mse_acc = (double*)d_ws;
    int*                cnt     = (int*)((char*)d_ws + 64);
    float*              enorm   = (float*)((char*)d_ws + 64 + 4096);
    unsigned long long* best    = (unsigned long long*)((char*)d_ws + 64 + 4096 + 4096);
    const size_t small_end = ((64 + 4096 + 4096 + (size_t)NROWS * 8) + 255) & ~(size_t)255;

    const size_t zsplit = (size_t)NROWS * ED * 2;   // 8 MB per array
    const size_t esplit = (size_t)NE * ED * 2;      // 0.5 MB per array
    half_t *zh, *zl, *eh, *el;
    if (ws_size >= small_end + 2 * zsplit + 2 * esplit) {
        char* big = (char*)d_ws + small_end;
        zh = (half_t*)big;
        zl = (half_t*)(big + zsplit);
        eh = (half_t*)(big + 2 * zsplit);
        el = (half_t*)(big + 2 * zsplit + esplit);
    } else {
        // stash zh/zl in the z_q_st region of d_out (consumed by vq_gemm before
        // vq_out overwrites it); eh/el in the small ws region.
        zh = (half_t*)((char*)d_out + 8);
        zl = (half_t*)((char*)d_out + 8 + zsplit);
        eh = (half_t*)((char*)d_ws + small_end);
        el = (half_t*)((char*)d_ws + small_end + esplit);
    }

    vq_split<<<(NROWS * ED / 4 + NE * ED / 4) / 256, 256, 0, stream>>>(
        z, emb, zh, zl, eh, el, best, cnt, mse_acc);
    vq_enorm<<<256, 256, 0, stream>>>(emb, enorm);
    vq_gemm<<<dim3(NROWS / 128, NE / 128), 256, 0, stream>>>(
        zh, zl, eh, el, u, enorm, best);
    vq_out<<<NROWS / 64, 256, 0, stream>>>(z, emb, best, cnt, mse_acc, out);
    vq_final<<<1, 1024, 0, stream>>>(cnt, mse_acc, out);
}